// Round 3
// baseline (161.684 us; speedup 1.0000x reference)
//
#include <hip/hip_runtime.h>

#define BINS 4096            // 64 * 64
#define HIST_BLOCKS 1024
#define HIST_THREADS 512     // 8 waves/block, 4 blocks/CU -> 32 waves/CU
#define PAIRS 4              // int4-pairs per thread per iteration (8 loads in flight)

#define RED_THREADS 256
#define RED_SPLITS 32        // each reduce block sums HIST_BLOCKS/RED_SPLITS = 32 rows

// out[i] = transitions_in[i] for i < bins; out[bins] = total_in + n_events
__global__ void topo_init_kernel(const float* __restrict__ transitions,
                                 const float* __restrict__ total,
                                 float* __restrict__ out,
                                 float n_events_f, int bins) {
    int i = blockIdx.x * blockDim.x + threadIdx.x;
    if (i < bins) out[i] = transitions[i];
    if (i == 0) out[bins] = total[0] + n_events_f;
}

template <bool USE_WS>
__global__ void __launch_bounds__(HIST_THREADS)
topo_hist_kernel(const int* __restrict__ prev,
                 const int* __restrict__ curr,
                 float* __restrict__ out,
                 unsigned* __restrict__ ws, int n) {
    __shared__ unsigned h[BINS];
    for (int i = threadIdx.x; i < BINS; i += HIST_THREADS) h[i] = 0u;
    __syncthreads();

    const int n4 = n >> 2;
    const int4* __restrict__ p4 = (const int4*)prev;
    const int4* __restrict__ c4 = (const int4*)curr;

    const int chunk  = HIST_THREADS * PAIRS;
    const int stride = gridDim.x * chunk;

    for (int cstart = blockIdx.x * chunk; cstart < n4; cstart += stride) {
        const int i0 = cstart + threadIdx.x;
        int4 p[PAIRS], c[PAIRS];
        bool ok[PAIRS];
#pragma unroll
        for (int j = 0; j < PAIRS; j++) {
            const int idx = i0 + j * HIST_THREADS;
            ok[j] = (idx < n4);
            if (ok[j]) { p[j] = p4[idx]; c[j] = c4[idx]; }
        }
#pragma unroll
        for (int j = 0; j < PAIRS; j++) {
            if (ok[j]) {
                atomicAdd(&h[(p[j].x << 6) | c[j].x], 1u);
                atomicAdd(&h[(p[j].y << 6) | c[j].y], 1u);
                atomicAdd(&h[(p[j].z << 6) | c[j].z], 1u);
                atomicAdd(&h[(p[j].w << 6) | c[j].w], 1u);
            }
        }
    }
    // scalar tail (n % 4 != 0 — not hit for 16.7M but kept for safety)
    for (int i = (n4 << 2) + blockIdx.x * HIST_THREADS + threadIdx.x; i < n;
         i += gridDim.x * HIST_THREADS) {
        atomicAdd(&h[(prev[i] << 6) | curr[i]], 1u);
    }

    __syncthreads();
    if (USE_WS) {
        // plain coalesced store of the per-block histogram — no atomics
        uint4* __restrict__ dst = (uint4*)(ws + (size_t)blockIdx.x * BINS);
        const uint4* __restrict__ src = (const uint4*)h;
        for (int i = threadIdx.x; i < BINS / 4; i += HIST_THREADS) dst[i] = src[i];
    } else {
        for (int i = threadIdx.x; i < BINS; i += HIST_THREADS) {
            unsigned cnt = h[i];
            if (cnt) atomicAdd(&out[i], (float)cnt);
        }
    }
}

// 512 blocks: 16 bin-groups x 32 splits. Each block sums 32 rows for 256 bins
// (coalesced), then one float atomicAdd per bin (depth 32 per address).
__global__ void __launch_bounds__(RED_THREADS)
topo_reduce_kernel(const unsigned* __restrict__ ws, float* __restrict__ out) {
    const int groups = BINS / RED_THREADS;            // 16
    const int bin_group = blockIdx.x % groups;
    const int split     = blockIdx.x / groups;        // 0..31
    const int bin = bin_group * RED_THREADS + threadIdx.x;
    const int rows = HIST_BLOCKS / RED_SPLITS;        // 32
    const int r0 = split * rows;
    unsigned sum = 0;
#pragma unroll 8
    for (int j = 0; j < rows; j++)
        sum += ws[(size_t)(r0 + j) * BINS + bin];
    if (sum) atomicAdd(&out[bin], (float)sum);
}

extern "C" void kernel_launch(void* const* d_in, const int* in_sizes, int n_in,
                              void* d_out, int out_size, void* d_ws, size_t ws_size,
                              hipStream_t stream) {
    const int*   prev        = (const int*)d_in[0];
    const int*   curr        = (const int*)d_in[1];
    const float* transitions = (const float*)d_in[2];
    const float* total       = (const float*)d_in[3];
    float* out = (float*)d_out;

    const int n    = in_sizes[0];
    const int bins = in_sizes[2];   // 4096

    // 1) initialize output: copy transitions input, set total = total_in + n
    int init_blocks = (bins + 1 + 255) / 256;
    topo_init_kernel<<<init_blocks, 256, 0, stream>>>(transitions, total, out,
                                                      (float)n, bins);

    const size_t ws_needed = (size_t)HIST_BLOCKS * BINS * sizeof(unsigned);
    if (ws_size >= ws_needed && bins == BINS) {
        // 2) per-block LDS histogram, flushed as plain stores to workspace
        topo_hist_kernel<true><<<HIST_BLOCKS, HIST_THREADS, 0, stream>>>(
            prev, curr, out, (unsigned*)d_ws, n);
        // 3) tree-reduce partials into out (shallow atomic depth = 32)
        topo_reduce_kernel<<<(BINS / RED_THREADS) * RED_SPLITS, RED_THREADS, 0,
                             stream>>>((unsigned*)d_ws, out);
    } else {
        // fallback: atomic flush directly into out
        topo_hist_kernel<false><<<HIST_BLOCKS, HIST_THREADS, 0, stream>>>(
            prev, curr, out, nullptr, n);
    }
}